// Round 19
// baseline (21.490 us; speedup 1.0000x reference)
//
#include <hip/hip_runtime.h>
#include <cmath>

#define LLEN 131072
#define IIRL 16384
#define SEG  1024             // one wave owns one segment, fully independent
#define SPR  (LLEN / SEG)     // 128 segments per row
#define TPB  256
#define WPB  (TPB / 64)       // 4 waves per block
// layout within a segment: elem i = 4*(64*q + lane) + m, q,m in [0,4)
// -> every float4 load/store is lane-contiguous (64 lanes x 16B = 1KiB)

typedef float floatx4 __attribute__((ext_vector_type(4)));

__device__ __forceinline__ float powiu(float b, unsigned e) {
    float r = 1.0f;
    while (e) { if (e & 1u) r *= b; b *= b; e >>= 1; }
    return r;
}

// native base-2 transcendentals (v_exp_f32 / v_log_f32)
__device__ __forceinline__ float exp2_hw(float x) { return __builtin_amdgcn_exp2f(x); }
__device__ __forceinline__ float log2_hw(float x) { return __builtin_amdgcn_logf(x); }

// weighted total of one 1024-sample segment, loading from global (rare paths)
__device__ __forceinline__ float seg_total(
    const float4* __restrict__ r0, const float4* __restrict__ r1,
    int lane, float alpha, float omah, float a4, float a256)
{
    float4 pa[4], pb[4];
    #pragma unroll
    for (int q = 0; q < 4; ++q) { pa[q] = r0[q*64+lane]; pb[q] = r1[q*64+lane]; }
    float u = 0.0f;
    #pragma unroll
    for (int q = 0; q < 4; ++q) {
        float4 ta = pa[q], tc = pb[q];
        float s = omah * fmaf(ta.x, ta.x, tc.x * tc.x);
        s = fmaf(alpha, s, omah * fmaf(ta.y, ta.y, tc.y * tc.y));
        s = fmaf(alpha, s, omah * fmaf(ta.z, ta.z, tc.z * tc.z));
        s = fmaf(alpha, s, omah * fmaf(ta.w, ta.w, tc.w * tc.w));
        u = fmaf(a256, u, s);              // Horner over q-groups
    }
    u *= powiu(a4, (unsigned)(63 - lane)); // lane weight
    #pragma unroll
    for (int off = 32; off; off >>= 1) u += __shfl_xor(u, off, 64);
    return u;
}

// ---------------------------------------------------------------------------
// R18 = R17 + latency-hiding reorder: issue ALL loads (own seg + prev seg)
// up-front into registers; run the full own-side pipeline (b, rt, 4-way wave
// scan) while prev loads complete; only then fold prev into the carry.
// carry(g) = T(g-1) (+ A1024^k-weighted deeper terms when representable —
// runtime wk==0 guard keeps this exact for ALL alpha).
// No LDS, no __syncthreads, no cross-block communication.
// gain = (1+u)^coef, u = exp2(knee*log2(env+eps) + C0), C0 = -knee*T*log2e
// env[t] = a*env[t-1] + (1-a)*(ls[t] - a^16384*ls[t-16384]), ls = mean_c(x^2)
// ---------------------------------------------------------------------------
__global__ __launch_bounds__(TPB, 4) void k_fused(
    const float* __restrict__ x, const float* __restrict__ za,
    const float* __restrict__ lt, const float* __restrict__ lr,
    const float* __restrict__ lk, float* __restrict__ out)
{
    const int lane = threadIdx.x & 63, wid = threadIdx.x >> 6;
    // XCD-aware bijective swizzle: consecutive segments of a row -> same XCD
    const int per = gridDim.x >> 3;                   // gridDim.x % 8 == 0
    const int bsw = (blockIdx.x & 7) * per + (blockIdx.x >> 3);
    const int g   = bsw * WPB + wid;                  // global segment id
    const int n   = g >> 7, s = g & (SPR - 1);        // row, segment-in-row

    const float alpha = 1.0f / (1.0f + __expf(-za[n]));
    const float omah  = 0.5f * (1.0f - alpha);
    const float A16K  = powiu(alpha, IIRL);   // 0 unless alpha > 0.9947
    const float LOG2E = 1.4426950408889634f;
    const float Tthr  = lt[n] - 6.0f;
    const float ratio = 1.0f + __expf(lr[n]);
    const float knee  = __expf(lk[n] - 1.0f);
    const float coef  = (1.0f / ratio - 1.0f) / knee;
    const float C0    = -knee * Tthr * LOG2E;

    const float a4    = (alpha * alpha) * (alpha * alpha);
    const float a256  = powiu(a4, 64u);
    const float A1024 = powiu(a256, 4u);      // may be tiny-but-nonzero

    const long base = (long)n * 2 * LLEN + (long)s * SEG;
    const float* x0 = x + base;
    const float* x1 = x0 + LLEN;

    // ---- phase 1: issue ALL loads up-front (own + prev segment) ----
    float4 xa[4], xb[4], pa[4], pb[4];
    {
        const float4* p0 = reinterpret_cast<const float4*>(x0);
        const float4* p1 = reinterpret_cast<const float4*>(x1);
        #pragma unroll
        for (int q = 0; q < 4; ++q) {
            xa[q] = p0[q * 64 + lane];
            xb[q] = p1[q * 64 + lane];
        }
    }
    const bool hasPrev = (s > 0);
    if (hasPrev) {
        const float4* r0 = reinterpret_cast<const float4*>(x0 - SEG);
        const float4* r1 = reinterpret_cast<const float4*>(x1 - SEG);
        #pragma unroll
        for (int q = 0; q < 4; ++q) {
            pa[q] = r0[q * 64 + lane];
            pb[q] = r1[q * 64 + lane];
        }
    }

    // ---- phase 2: own-side pipeline (prev loads complete underneath) ----
    float b[4][4];
    #pragma unroll
    for (int q = 0; q < 4; ++q) {
        float4 a = xa[q], c = xb[q];
        b[q][0] = omah * fmaf(a.x, a.x, c.x * c.x);
        b[q][1] = omah * fmaf(a.y, a.y, c.y * c.y);
        b[q][2] = omah * fmaf(a.z, a.z, c.z * c.z);
        b[q][3] = omah * fmaf(a.w, a.w, c.w * c.w);
    }
    if (A16K != 0.0f && s >= 16) {            // rare exact truncation tail
        const float4* t0p = reinterpret_cast<const float4*>(x0 - IIRL);
        const float4* t1p = reinterpret_cast<const float4*>(x1 - IIRL);
        const float sc = A16K * omah;
        #pragma unroll
        for (int q = 0; q < 4; ++q) {
            float4 ta = t0p[q * 64 + lane], tc = t1p[q * 64 + lane];
            b[q][0] -= sc * fmaf(ta.x, ta.x, tc.x * tc.x);
            b[q][1] -= sc * fmaf(ta.y, ta.y, tc.y * tc.y);
            b[q][2] -= sc * fmaf(ta.z, ta.z, tc.z * tc.z);
            b[q][3] -= sc * fmaf(ta.w, ta.w, tc.w * tc.w);
        }
    }

    float rt[4];
    #pragma unroll
    for (int q = 0; q < 4; ++q) {
        float sv = b[q][0];
        sv = fmaf(alpha, sv, b[q][1]);
        sv = fmaf(alpha, sv, b[q][2]);
        sv = fmaf(alpha, sv, b[q][3]);
        rt[q] = sv;
    }

    float v0 = rt[0], v1 = rt[1], v2 = rt[2], v3 = rt[3];
    float gg = a4;
    #pragma unroll
    for (int off = 1; off < 64; off <<= 1) {
        float y0 = __shfl_up(v0, off, 64);
        float y1 = __shfl_up(v1, off, 64);
        float y2 = __shfl_up(v2, off, 64);
        float y3 = __shfl_up(v3, off, 64);
        if (lane >= off) {
            v0 = fmaf(gg, y0, v0); v1 = fmaf(gg, y1, v1);
            v2 = fmaf(gg, y2, v2); v3 = fmaf(gg, y3, v3);
        }
        gg *= gg;
    }
    float Ex[4];
    Ex[0] = __shfl_up(v0, 1, 64); Ex[1] = __shfl_up(v1, 1, 64);
    Ex[2] = __shfl_up(v2, 1, 64); Ex[3] = __shfl_up(v3, 1, 64);
    if (lane == 0) { Ex[0] = Ex[1] = Ex[2] = Ex[3] = 0.0f; }
    float S[4];
    S[0] = __shfl(v0, 63, 64); S[1] = __shfl(v1, 63, 64);
    S[2] = __shfl(v2, 63, 64); S[3] = __shfl(v3, 63, 64);

    // ---- phase 3: fold prev segment into carry (loads long since done) ----
    float carry = 0.0f;
    if (hasPrev) {
        float u = 0.0f;
        #pragma unroll
        for (int q = 0; q < 4; ++q) {
            float4 ta = pa[q], tc = pb[q];
            float sv = omah * fmaf(ta.x, ta.x, tc.x * tc.x);
            sv = fmaf(alpha, sv, omah * fmaf(ta.y, ta.y, tc.y * tc.y));
            sv = fmaf(alpha, sv, omah * fmaf(ta.z, ta.z, tc.z * tc.z));
            sv = fmaf(alpha, sv, omah * fmaf(ta.w, ta.w, tc.w * tc.w));
            u = fmaf(a256, u, sv);
        }
        u *= powiu(a4, (unsigned)(63 - lane));
        #pragma unroll
        for (int off = 32; off; off >>= 1) u += __shfl_xor(u, off, 64);
        carry = u;
    }
    if (A1024 != 0.0f && s > 1) {             // deep carry (alpha extreme)
        float wk = A1024;
        for (int k = 2; k <= 16; ++k) {
            if (s - k < 0 || wk == 0.0f) break;
            float Tk = seg_total(
                reinterpret_cast<const float4*>(x0 - (long)k * SEG),
                reinterpret_cast<const float4*>(x1 - (long)k * SEG),
                lane, alpha, omah, a4, a256);
            carry = fmaf(wk, Tk, carry);
            wk *= A1024;
        }
    }

    const float a4l = powiu(a4, (unsigned)lane);

    // ---- apply gain + non-temporal coalesced writes ----
    float cq = carry;                     // env prefix before run-block q
    floatx4* o0 = reinterpret_cast<floatx4*>(out + base);
    floatx4* o1 = reinterpret_cast<floatx4*>(out + base + LLEN);
    #pragma unroll
    for (int q = 0; q < 4; ++q) {
        float e = fmaf(a4l, cq, Ex[q]);   // env before this thread's run
        cq = fmaf(a256, cq, S[q]);        // advance to next run block
        float4 a = xa[q], c = xb[q];
        floatx4 oa, ob;
        const float* ia = reinterpret_cast<const float*>(&a);
        const float* ib = reinterpret_cast<const float*>(&c);
        #pragma unroll
        for (int m = 0; m < 4; ++m) {
            e = fmaf(alpha, e, b[q][m]);
            float t  = fmaf(knee, log2_hw(e + 1e-5f), C0);
            float u  = exp2_hw(t);
            float sp = log2_hw(1.0f + u);
            float gain = exp2_hw(coef * sp);
            oa[m] = gain * ia[m];
            ob[m] = gain * ib[m];
        }
        __builtin_nontemporal_store(oa, &o0[q * 64 + lane]);
        __builtin_nontemporal_store(ob, &o1[q * 64 + lane]);
    }
}

extern "C" void kernel_launch(void* const* d_in, const int* in_sizes, int n_in,
                              void* d_out, int out_size, void* d_ws, size_t ws_size,
                              hipStream_t stream) {
    const float* x  = (const float*)d_in[0];
    const float* za = (const float*)d_in[1];
    const float* lt = (const float*)d_in[2];
    const float* lr = (const float*)d_in[3];
    const float* lk = (const float*)d_in[4];
    float* out = (float*)d_out;

    const int N = in_sizes[1];             // z_alpha is (N,1)
    const int nblk = N * SPR / WPB;        // one wave per segment (N*32 blocks)
    k_fused<<<dim3(nblk), dim3(TPB), 0, stream>>>(x, za, lt, lr, lk, out);
}

// Round 20
// 13.555 us; speedup vs baseline: 1.5854x; 1.5854x over previous
//
#include <hip/hip_runtime.h>
#include <cmath>

#define LLEN 131072
#define IIRL 16384
#define SEG  1024             // one wave owns one segment, fully independent
#define SPR  (LLEN / SEG)     // 128 segments per row
#define TPB  256
#define WPB  (TPB / 64)       // 4 waves per block
// layout within a segment: elem i = 4*(64*q + lane) + m, q,m in [0,4)
// -> every float4 load/store is lane-contiguous (64 lanes x 16B = 1KiB)

typedef float floatx4 __attribute__((ext_vector_type(4)));

__device__ __forceinline__ float powiu(float b, unsigned e) {
    float r = 1.0f;
    while (e) { if (e & 1u) r *= b; b *= b; e >>= 1; }
    return r;
}

// native base-2 transcendentals (v_exp_f32 / v_log_f32)
__device__ __forceinline__ float exp2_hw(float x) { return __builtin_amdgcn_exp2f(x); }
__device__ __forceinline__ float log2_hw(float x) { return __builtin_amdgcn_logf(x); }

// weighted total of one 1024-sample segment (zero-init chain):
//   T = sum_i alpha^(1023-i) * omah*(x0[i]^2 + x1[i]^2)
__device__ __forceinline__ float seg_total(
    const float4* __restrict__ r0, const float4* __restrict__ r1,
    int lane, float alpha, float omah, float a4, float a256)
{
    float4 pa[4], pb[4];
    #pragma unroll
    for (int q = 0; q < 4; ++q) { pa[q] = r0[q*64+lane]; pb[q] = r1[q*64+lane]; }
    float u = 0.0f;
    #pragma unroll
    for (int q = 0; q < 4; ++q) {
        float4 ta = pa[q], tc = pb[q];
        float s = omah * fmaf(ta.x, ta.x, tc.x * tc.x);
        s = fmaf(alpha, s, omah * fmaf(ta.y, ta.y, tc.y * tc.y));
        s = fmaf(alpha, s, omah * fmaf(ta.z, ta.z, tc.z * tc.z));
        s = fmaf(alpha, s, omah * fmaf(ta.w, ta.w, tc.w * tc.w));
        u = fmaf(a256, u, s);              // Horner over q-groups
    }
    u *= powiu(a4, (unsigned)(63 - lane)); // lane weight
    #pragma unroll
    for (int off = 32; off; off >>= 1) u += __shfl_xor(u, off, 64);
    return u;
}

// ---------------------------------------------------------------------------
// R20 = exact revert to R17 (best: 13.6us). R18's up-front prev loads spilled
// registers (pa/pb live across the scan under the 128-VGPR cap) -> 21.5us.
// R17: fully wave-independent (no LDS, no __syncthreads, no block coupling).
// carry(g) = T(g-1): deeper segment totals carry Horner coefficients
// A1024^k = (alpha^1024)^k which underflow to exactly 0.0f for realistic
// alpha — identical arithmetic to the block-combine versions. Rare alpha
// paths (A1024!=0: deep carry loop; A16K!=0: exact b-tail from seg g-16)
// stay exact and wave-uniform.
// gain = (1+u)^coef, u = exp2(knee*log2(env+eps) + C0), C0 = -knee*T*log2e
// env[t] = a*env[t-1] + (1-a)*(ls[t] - a^16384*ls[t-16384]), ls = mean_c(x^2)
// ---------------------------------------------------------------------------
__global__ __launch_bounds__(TPB) void k_fused(
    const float* __restrict__ x, const float* __restrict__ za,
    const float* __restrict__ lt, const float* __restrict__ lr,
    const float* __restrict__ lk, float* __restrict__ out)
{
    const int lane = threadIdx.x & 63, wid = threadIdx.x >> 6;
    // XCD-aware bijective swizzle: consecutive segments of a row -> same XCD
    const int per = gridDim.x >> 3;                   // gridDim.x % 8 == 0
    const int bsw = (blockIdx.x & 7) * per + (blockIdx.x >> 3);
    const int g   = bsw * WPB + wid;                  // global segment id
    const int n   = g >> 7, s = g & (SPR - 1);        // row, segment-in-row

    const float alpha = 1.0f / (1.0f + __expf(-za[n]));
    const float omah  = 0.5f * (1.0f - alpha);
    const float A16K  = powiu(alpha, IIRL);   // 0 unless alpha > 0.9947
    const float LOG2E = 1.4426950408889634f;
    const float Tthr  = lt[n] - 6.0f;
    const float ratio = 1.0f + __expf(lr[n]);
    const float knee  = __expf(lk[n] - 1.0f);
    const float coef  = (1.0f / ratio - 1.0f) / knee;
    const float C0    = -knee * Tthr * LOG2E;

    const float a4    = (alpha * alpha) * (alpha * alpha);
    const float a256  = powiu(a4, 64u);
    const float A1024 = powiu(a256, 4u);      // 0 unless alpha > ~0.9993

    const long base = (long)n * 2 * LLEN + (long)s * SEG;
    const float* x0 = x + base;
    const float* x1 = x0 + LLEN;

    // ---- own-segment loads (issued first, max MLP) ----
    float4 xa[4], xb[4];
    {
        const float4* p0 = reinterpret_cast<const float4*>(x0);
        const float4* p1 = reinterpret_cast<const float4*>(x1);
        #pragma unroll
        for (int q = 0; q < 4; ++q) {
            xa[q] = p0[q * 64 + lane];
            xb[q] = p1[q * 64 + lane];
        }
    }

    // ---- carry = T(g-1) (prev-seg loads overlap own-side compute) ----
    float carry = 0.0f;
    if (s > 0) {
        carry = seg_total(reinterpret_cast<const float4*>(x0 - SEG),
                          reinterpret_cast<const float4*>(x1 - SEG),
                          lane, alpha, omah, a4, a256);
    }

    // ---- b values (recurrence input) ----
    float b[4][4];
    #pragma unroll
    for (int q = 0; q < 4; ++q) {
        float4 a = xa[q], c = xb[q];
        b[q][0] = omah * fmaf(a.x, a.x, c.x * c.x);
        b[q][1] = omah * fmaf(a.y, a.y, c.y * c.y);
        b[q][2] = omah * fmaf(a.z, a.z, c.z * c.z);
        b[q][3] = omah * fmaf(a.w, a.w, c.w * c.w);
    }

    // ---- rare exact paths (wave-uniform; alpha extreme) ----
    if (A16K != 0.0f && s >= 16) {            // exact truncation tail
        const float4* t0p = reinterpret_cast<const float4*>(x0 - IIRL);
        const float4* t1p = reinterpret_cast<const float4*>(x1 - IIRL);
        const float sc = A16K * omah;
        #pragma unroll
        for (int q = 0; q < 4; ++q) {
            float4 ta = t0p[q * 64 + lane], tc = t1p[q * 64 + lane];
            b[q][0] -= sc * fmaf(ta.x, ta.x, tc.x * tc.x);
            b[q][1] -= sc * fmaf(ta.y, ta.y, tc.y * tc.y);
            b[q][2] -= sc * fmaf(ta.z, ta.z, tc.z * tc.z);
            b[q][3] -= sc * fmaf(ta.w, ta.w, tc.w * tc.w);
        }
    }
    if (A1024 != 0.0f && s > 1) {             // deep carry (alpha > ~0.9993)
        float wk = A1024;
        for (int k = 2; k <= 16; ++k) {
            if (s - k < 0 || wk == 0.0f) break;
            float Tk = seg_total(
                reinterpret_cast<const float4*>(x0 - (long)k * SEG),
                reinterpret_cast<const float4*>(x1 - (long)k * SEG),
                lane, alpha, omah, a4, a256);
            carry = fmaf(wk, Tk, carry);
            wk *= A1024;
        }
    }

    // ---- per-thread run totals (4 independent chains) ----
    float rt[4];
    #pragma unroll
    for (int q = 0; q < 4; ++q) {
        float sv = b[q][0];
        sv = fmaf(alpha, sv, b[q][1]);
        sv = fmaf(alpha, sv, b[q][2]);
        sv = fmaf(alpha, sv, b[q][3]);
        rt[q] = sv;
    }

    // ---- 4 interleaved wave scans over lanes (ratio a^4) ----
    float v0 = rt[0], v1 = rt[1], v2 = rt[2], v3 = rt[3];
    float gg = a4;
    #pragma unroll
    for (int off = 1; off < 64; off <<= 1) {
        float y0 = __shfl_up(v0, off, 64);
        float y1 = __shfl_up(v1, off, 64);
        float y2 = __shfl_up(v2, off, 64);
        float y3 = __shfl_up(v3, off, 64);
        if (lane >= off) {
            v0 = fmaf(gg, y0, v0); v1 = fmaf(gg, y1, v1);
            v2 = fmaf(gg, y2, v2); v3 = fmaf(gg, y3, v3);
        }
        gg *= gg;
    }
    float Ex[4];
    Ex[0] = __shfl_up(v0, 1, 64); Ex[1] = __shfl_up(v1, 1, 64);
    Ex[2] = __shfl_up(v2, 1, 64); Ex[3] = __shfl_up(v3, 1, 64);
    if (lane == 0) { Ex[0] = Ex[1] = Ex[2] = Ex[3] = 0.0f; }
    float S[4];
    S[0] = __shfl(v0, 63, 64); S[1] = __shfl(v1, 63, 64);
    S[2] = __shfl(v2, 63, 64); S[3] = __shfl(v3, 63, 64);

    const float a4l = powiu(a4, (unsigned)lane);

    // ---- apply gain + non-temporal coalesced writes ----
    float cq = carry;                     // env prefix before run-block q
    floatx4* o0 = reinterpret_cast<floatx4*>(out + base);
    floatx4* o1 = reinterpret_cast<floatx4*>(out + base + LLEN);
    #pragma unroll
    for (int q = 0; q < 4; ++q) {
        float e = fmaf(a4l, cq, Ex[q]);   // env before this thread's run
        cq = fmaf(a256, cq, S[q]);        // advance to next run block
        float4 a = xa[q], c = xb[q];
        floatx4 oa, ob;
        const float* ia = reinterpret_cast<const float*>(&a);
        const float* ib = reinterpret_cast<const float*>(&c);
        #pragma unroll
        for (int m = 0; m < 4; ++m) {
            e = fmaf(alpha, e, b[q][m]);
            float t  = fmaf(knee, log2_hw(e + 1e-5f), C0);
            float u  = exp2_hw(t);
            float sp = log2_hw(1.0f + u);
            float gain = exp2_hw(coef * sp);
            oa[m] = gain * ia[m];
            ob[m] = gain * ib[m];
        }
        __builtin_nontemporal_store(oa, &o0[q * 64 + lane]);
        __builtin_nontemporal_store(ob, &o1[q * 64 + lane]);
    }
}

extern "C" void kernel_launch(void* const* d_in, const int* in_sizes, int n_in,
                              void* d_out, int out_size, void* d_ws, size_t ws_size,
                              hipStream_t stream) {
    const float* x  = (const float*)d_in[0];
    const float* za = (const float*)d_in[1];
    const float* lt = (const float*)d_in[2];
    const float* lr = (const float*)d_in[3];
    const float* lk = (const float*)d_in[4];
    float* out = (float*)d_out;

    const int N = in_sizes[1];             // z_alpha is (N,1)
    const int nblk = N * SPR / WPB;        // one wave per segment (N*32 blocks)
    k_fused<<<dim3(nblk), dim3(TPB), 0, stream>>>(x, za, lt, lr, lk, out);
}